// Round 5
// baseline (293.186 us; speedup 1.0000x reference)
//
#include <hip/hip_runtime.h>
#include <hip/hip_bf16.h>
#include <stdint.h>
#include <stddef.h>

// Problem: B=4096, E=16, D=512, H=2048
// out[b,h] = sum_e relu( x_b . W[e,h,:] - c_e . W[e,h,:] + b[e,h] )
// GEMM view: M=4096, N=E*H (expert-looped), K=512. 137.4 GFLOP.
// History: R6 128x64 2-barrier gemm 167us; R7 counted-vmcnt graft FAILED
//   (occupancy); R8/R9 prep residual ~95-110us invariant across 4 prep
//   rewrites AND full fusion -> prep's W->bf16 conversion path runs at
//   ~1.1 TB/s effective no matter what; R10 256x128 BK=64 3-buf counted
//   vmcnt gemm = 152us (works, +10%), total still 262.
// R11: DELETE the W prepass. B-staging inside the gemm reg-stages fp32 W
//   (issue loads for tile g+1 at top of iter g, cvt+ds_write at bottom,
//   T14 split), accumulating cw[e,h] = c_e.W_row partials in fp32 on the
//   fly; 8-lane shfl tree finalizes cw one iteration before the merge
//   uses it (bias2 = bias - cw, full fp32 precision preserved).
//   Only remaining prepass: X -> bf16 (12 MB, ~4us).
//   vmcnt: compiler's reg-wait for B-regs drains the older A-async(g+1);
//   explicit vmcnt(4) leaves A-async(g+2) in flight across the barrier.
//   XCD swizzle flipped to hi-major per XCD so the 16 same-hi blocks on
//   one XCD share the fp32 W panel in L2.

#define B_DIM 4096
#define E_DIM 16
#define D_DIM 512
#define H_DIM 2048

typedef short bf16x8 __attribute__((ext_vector_type(8)));
typedef short bf16x4 __attribute__((ext_vector_type(4)));
typedef float f32x4 __attribute__((ext_vector_type(4)));

__device__ __forceinline__ short f2bf(float f) {
  __hip_bfloat16 h = __float2bfloat16(f);  // RNE
  return *reinterpret_cast<short*>(&h);
}

__device__ __forceinline__ bf16x8 cvt8(float4 a, float4 b) {
  bf16x8 v;
  v[0] = f2bf(a.x); v[1] = f2bf(a.y); v[2] = f2bf(a.z); v[3] = f2bf(a.w);
  v[4] = f2bf(b.x); v[5] = f2bf(b.y); v[6] = f2bf(b.z); v[7] = f2bf(b.w);
  return v;
}

__device__ __forceinline__ float dot4(float4 a, float4 b) {
  return a.x * b.x + a.y * b.y + a.z * b.z + a.w * b.w;
}

// async global->LDS, 16 bytes per lane. LDS dest must be uniform_base + lane*16.
__device__ __forceinline__ void async_copy16(const void* gptr, void* lptr) {
  __builtin_amdgcn_global_load_lds(
      (const __attribute__((address_space(1))) void*)gptr,
      (__attribute__((address_space(3))) void*)lptr,
      16, 0, 0);
}

// ---------------------------------------------------------------------------
// X -> bf16 only. 1024 blocks x 256 thr x 8 floats = 2,097,152 = B*D.
// ---------------------------------------------------------------------------
__global__ __launch_bounds__(256) void prep_x(
    const float* __restrict__ X, __hip_bfloat16* __restrict__ Xb) {
  const size_t t = (size_t)blockIdx.x * 256 + threadIdx.x;
  const size_t i0 = t * 8;
  float4 a0 = *(const float4*)(X + i0);
  float4 a1 = *(const float4*)(X + i0 + 4);
  *(bf16x8*)(Xb + i0) = cvt8(a0, a1);
}

// ---------------------------------------------------------------------------
// R11 GEMM. Tile 256x128, BK=64, 512 thr, 8 waves (4Mx2N), 64x64/wave.
// K-tiles g = e*8 + k, g in [0,128). 3 LDS buffers rotate (49152 B each:
// A 32768 + B 16384). Slot s of row r holds global k-chunk s^(r&7)
// (R10-verified swizzle, 0 bank conflicts).
// Iter g: [LOADB(g+1) regs][STAGEA(g+2) async][MFMA on buf g][merge @g&7==7]
//         [PROCB: cvt W regs -> buf g+1 B + cw FMA][vmcnt(4) barrier].
// LDS map: bufs @0/49152/98304; biasS f32[16][128] @147456; cwF f32[128]
// @155648. Total 156160 B (1 block/CU).
// ---------------------------------------------------------------------------
__global__ __launch_bounds__(512, 2) void moe_gemm9(
    const __hip_bfloat16* __restrict__ Xb,   // [4096, 512] bf16
    const float* __restrict__ W,             // [16, 2048, 512] fp32
    const float* __restrict__ C,             // [16, 512] fp32
    const float* __restrict__ bias,          // [16, 2048] fp32
    float* __restrict__ out) {               // [4096, 2048]
  __shared__ __align__(16) char smem[156160];

  const int tid = threadIdx.x;
  const int lane = tid & 63;
  const int wave = tid >> 6;

  // bijective XCD swizzle; hi-major per XCD -> 16 same-hi blocks share the
  // fp32 W panel in that XCD's L2.
  const int swz = (blockIdx.x & 7) * 32 + (blockIdx.x >> 3);
  const int hi = swz >> 4;          // 16 h-tiles
  const int mi = swz & 15;          // 16 m-tiles
  const int m0 = mi * 256;
  const int h0 = hi * 128;

  const int wm = (wave >> 1) * 64;  // 4 m-groups
  const int wn = (wave & 1) * 64;   // 2 n-groups
  const int lm = lane & 15;
  const int q = lane >> 4;

  // ---- A staging (async from Xb): chunk n = j*512+tid, row r=n>>3,
  // LDS slot n&7 holds global chunk (n&7)^(r&7).
  int aSrc[4];
#pragma unroll
  for (int j = 0; j < 4; ++j) {
    const int n = j * 512 + tid;
    const int r = n >> 3;
    const int c = (n & 7) ^ (r & 7);
    aSrc[j] = r * D_DIM + c * 8;
  }

  // ---- B reg-staging geometry: j in {0,1}; n=j*512+tid; row r=n>>3
  // (j=0: 0..63, j=1: 64..127); global chunk c=(n&7)^(r&7); o=c*8 floats.
  const int rB0 = tid >> 3;  // row for j=0; j=1 row = 64+rB0
  int wOffE[2], oB[2];
#pragma unroll
  for (int j = 0; j < 2; ++j) {
    const int n = j * 512 + tid;
    const int r = n >> 3;
    const int c = (n & 7) ^ (r & 7);
    oB[j] = c * 8;
    wOffE[j] = r * D_DIM + c * 8;
  }

  // ---- read-side byte offsets: frag (row R, k-step s): chunk (s*4+q)
  // at slot ((s*4+q)^(R&7)).
  int aRd[4][2], bRd[4][2];
#pragma unroll
  for (int m = 0; m < 4; ++m) {
    const int R = wm + m * 16 + lm;
#pragma unroll
    for (int s = 0; s < 2; ++s)
      aRd[m][s] = R * 128 + (((s * 4 + q) ^ (R & 7)) << 4);
  }
#pragma unroll
  for (int n = 0; n < 4; ++n) {
    const int R = wn + n * 16 + lm;
#pragma unroll
    for (int s = 0; s < 2; ++s)
      bRd[n][s] = 32768 + R * 128 + (((s * 4 + q) ^ (R & 7)) << 4);
  }

  float* biasS = (float*)(smem + 147456);   // raw bias [16][128]
  float* cwF = (float*)(smem + 155648);     // per-expert cw [128]

#define STAGEA(bufOff, gg)                                                   \
  {                                                                          \
    const int k0 = ((gg) & 7) << 6;                                          \
    const __hip_bfloat16* Ag = Xb + (size_t)m0 * D_DIM + k0;                 \
    _Pragma("unroll")                                                        \
    for (int j = 0; j < 4; ++j)                                              \
      async_copy16(Ag + aSrc[j], smem + (bufOff) + (j * 512 + tid) * 16);    \
  }

  // NOTE: LOADB must be issued BEFORE STAGEA within an iteration so the
  // compiler's register wait for these loads leaves STAGEA(g+2) in flight.
#define LOADB(gg)                                                            \
  {                                                                          \
    const int k0 = ((gg) & 7) << 6;                                          \
    const float* Wg =                                                        \
        W + ((size_t)((gg) >> 3) << 20) + (size_t)h0 * D_DIM + k0;           \
    const float* Cg = C + (((gg) >> 3) << 9) + k0;                           \
    wA0 = *(const float4*)(Wg + wOffE[0]);                                   \
    wA1 = *(const float4*)(Wg + wOffE[0] + 4);                               \
    wB0 = *(const float4*)(Wg + wOffE[1]);                                   \
    wB1 = *(const float4*)(Wg + wOffE[1] + 4);                               \
    cA0 = *(const float4*)(Cg + oB[0]);                                      \
    cA1 = *(const float4*)(Cg + oB[0] + 4);                                  \
    cB0 = *(const float4*)(Cg + oB[1]);                                      \
    cB1 = *(const float4*)(Cg + oB[1] + 4);                                  \
  }

#define PROCB(bufOff)                                                        \
  {                                                                          \
    *(bf16x8*)(smem + (bufOff) + 32768 + tid * 16) = cvt8(wA0, wA1);         \
    *(bf16x8*)(smem + (bufOff) + 32768 + (512 + tid) * 16) = cvt8(wB0, wB1); \
    part0 += dot4(wA0, cA0) + dot4(wA1, cA1);                                \
    part1 += dot4(wB0, cB0) + dot4(wB1, cB1);                                \
  }

  float4 wA0, wA1, wB0, wB1, cA0, cA1, cB0, cB1;
  float part0 = 0.f, part1 = 0.f;

  // ---- prologue: A tiles 0,1 async; B tile 0 through regs; raw bias.
  STAGEA(0, 0);
  STAGEA(49152, 1);
  LOADB(0);
#pragma unroll
  for (int j = 0; j < 4; ++j) {
    const int idx = j * 512 + tid;  // e = idx>>7, col = idx&127
    biasS[idx] = bias[((idx >> 7) << 11) + h0 + (idx & 127)];
  }
  PROCB(0);  // compiler reg-wait drains STAGEA(0),STAGEA(1) too (prologue-only)
  asm volatile("s_waitcnt lgkmcnt(0)" ::: "memory");
  __builtin_amdgcn_s_barrier();
  __builtin_amdgcn_sched_barrier(0);

  f32x4 sum[4][4], acc[4][4];
#pragma unroll
  for (int m = 0; m < 4; ++m)
#pragma unroll
    for (int n = 0; n < 4; ++n) {
      sum[m][n] = (f32x4){0.f, 0.f, 0.f, 0.f};
      acc[m][n] = (f32x4){0.f, 0.f, 0.f, 0.f};
    }

  int bC = 0, bN = 49152, bS2 = 98304;  // compute g / B-write g+1 / A g+2

  for (int g = 0; g < 128; ++g) {
    if (g < 127) LOADB(g + 1);        // B regs for next tile (used at bottom)
    if (g < 126) STAGEA(bS2, g + 2);  // A async two tiles ahead

#pragma unroll
    for (int s = 0; s < 2; ++s) {
      bf16x8 aF[4], bF[4];
#pragma unroll
      for (int m = 0; m < 4; ++m)
        aF[m] = *(const bf16x8*)(smem + bC + aRd[m][s]);
#pragma unroll
      for (int n = 0; n < 4; ++n)
        bF[n] = *(const bf16x8*)(smem + bC + bRd[n][s]);
      asm volatile("s_waitcnt lgkmcnt(0)" ::: "memory");
      __builtin_amdgcn_sched_barrier(0);
      __builtin_amdgcn_s_setprio(1);
#pragma unroll
      for (int m = 0; m < 4; ++m)
#pragma unroll
        for (int n = 0; n < 4; ++n)
          acc[m][n] = __builtin_amdgcn_mfma_f32_16x16x32_bf16(
              aF[m], bF[n], acc[m][n], 0, 0, 0);
      __builtin_amdgcn_s_setprio(0);
    }

    if ((g & 7) == 7) {  // expert merge; cwF written at iter g-1, barriered
      const float* bS = biasS + ((g >> 3) << 7);
#pragma unroll
      for (int n = 0; n < 4; ++n) {
        const int col = wn + n * 16 + lm;
        const float bvn = bS[col] - cwF[col];
#pragma unroll
        for (int m = 0; m < 4; ++m)
#pragma unroll
          for (int u = 0; u < 4; ++u) {
            sum[m][n][u] += fmaxf(acc[m][n][u] + bvn, 0.f);
            acc[m][n][u] = 0.f;
          }
      }
    }

    if (g < 127) {
      PROCB(bN);  // compiler reg-wait drains A-async(g+1) (older) first
      if (((g + 1) & 7) == 7) {  // tile g+1 completes expert (g+1)>>3
        float p0 = part0, p1 = part1;
        p0 += __shfl_xor(p0, 1, 64);
        p0 += __shfl_xor(p0, 2, 64);
        p0 += __shfl_xor(p0, 4, 64);
        p1 += __shfl_xor(p1, 1, 64);
        p1 += __shfl_xor(p1, 2, 64);
        p1 += __shfl_xor(p1, 4, 64);
        if ((lane & 7) == 0) {
          cwF[rB0] = p0;
          cwF[64 + rB0] = p1;
        }
        part0 = 0.f;
        part1 = 0.f;
      }
    }

    // leave A-async(g+2) (4 loads) in flight across the barrier.
    asm volatile("s_waitcnt vmcnt(4) lgkmcnt(0)" ::: "memory");
    __builtin_amdgcn_s_barrier();
    __builtin_amdgcn_sched_barrier(0);

    const int t_ = bC; bC = bN; bN = bS2; bS2 = t_;
  }
#undef STAGEA
#undef LOADB
#undef PROCB

  // write: C/D layout col=lane&15, row=(lane>>4)*4+reg  [verified m89/m91]
#pragma unroll
  for (int m = 0; m < 4; ++m)
#pragma unroll
    for (int n = 0; n < 4; ++n)
#pragma unroll
      for (int u = 0; u < 4; ++u)
        out[(size_t)(m0 + wm + m * 16 + q * 4 + u) * H_DIM +
            h0 + wn + n * 16 + lm] = sum[m][n][u];
}

// ---------------------------------------------------------------------------
// Fallback (workspace too small): naive but correct fp32.
// ---------------------------------------------------------------------------
__global__ __launch_bounds__(256) void naive_kernel(
    const float* __restrict__ x, const float* __restrict__ c,
    const float* __restrict__ W, const float* __restrict__ bias,
    float* __restrict__ out) {
  const int idx = blockIdx.x * 256 + threadIdx.x;
  const int b = idx >> 11;
  const int h = idx & (H_DIM - 1);
  const float* xr = x + (size_t)b * D_DIM;
  float s = 0.f;
  for (int e = 0; e < E_DIM; ++e) {
    const float* wr = W + ((size_t)e * H_DIM + h) * D_DIM;
    const float* cr = c + (size_t)e * D_DIM;
    float acc = bias[e * H_DIM + h];
    for (int d = 0; d < D_DIM; ++d) acc += (xr[d] - cr[d]) * wr[d];
    s += fmaxf(acc, 0.f);
  }
  out[idx] = s;
}

extern "C" void kernel_launch(void* const* d_in, const int* in_sizes, int n_in,
                              void* d_out, int out_size, void* d_ws, size_t ws_size,
                              hipStream_t stream) {
  const float* x = (const float*)d_in[0];     // [4096, 512]
  const float* c = (const float*)d_in[1];     // [16, 512]
  const float* W = (const float*)d_in[2];     // [16, 2048, 512]
  const float* b = (const float*)d_in[3];     // [16, 2048]
  float* out = (float*)d_out;                 // [4096, 2048]

  const size_t sz_xb = (size_t)B_DIM * D_DIM * 2;  // 4 MB

  if (ws_size >= sz_xb) {
    __hip_bfloat16* Xb = (__hip_bfloat16*)d_ws;
    prep_x<<<1024, 256, 0, stream>>>(x, Xb);
    moe_gemm9<<<256, 512, 0, stream>>>(Xb, W, c, b, out);
  } else {
    naive_kernel<<<(B_DIM * H_DIM) / 256, 256, 0, stream>>>(x, c, W, b, out);
  }
}

// Round 6
// 264.600 us; speedup vs baseline: 1.1080x; 1.1080x over previous
//
#include <hip/hip_runtime.h>
#include <hip/hip_bf16.h>
#include <stdint.h>
#include <stddef.h>

// Problem: B=4096, E=16, D=512, H=2048
// out[b,h] = sum_e relu( x_b . W[e,h,:] - c_e . W[e,h,:] + b[e,h] )
// GEMM view: M=4096, N=E*H (expert-looped), K=512. 137.4 GFLOP.
// R6: 128x64 2-barrier gemm 167us. R7 counted-vmcnt graft FAILED (occup).
// R8/R9: prep residual ~95us invariant across 4 rewrites + fusion.
// R10: 256x128 BK=64 3-buf counted-vmcnt gemm: 152us (904 TF), MfmaUtil 38%,
//      0 conflicts, FETCH 133MB. Total still 262.
// R11 (FAILED): in-GEMM fp32-W conversion -> FETCH 293MB (16x fp32 re-read,
//      2x4MB panels thrash 4MB L2/XCD), gemm 220us. bf16 Wb prepass is the
//      cheaper feed. Reverted.
// R12: T3 phase-split on R10's skeleton: each K-tile = 2 barrier-bounded
//      phases {8 ds_read_b128 + stage-issue -> s_barrier -> lgkmcnt(0) ->
//      setprio(1) 16 MFMA setprio(0) -> s_barrier}; A-copies issued in
//      phase A, B-copies in phase B; counted vmcnt(6) at tile boundary
//      only (FIFO algebra identical to R10). T3 gates T5 (m218b +21-25%).

#define B_DIM 4096
#define E_DIM 16
#define D_DIM 512
#define H_DIM 2048

typedef short bf16x8 __attribute__((ext_vector_type(8)));
typedef short bf16x4 __attribute__((ext_vector_type(4)));
typedef float f32x4 __attribute__((ext_vector_type(4)));

__device__ __forceinline__ short f2bf(float f) {
  __hip_bfloat16 h = __float2bfloat16(f);  // RNE
  return *reinterpret_cast<short*>(&h);
}

__device__ __forceinline__ bf16x4 cvt4(float4 a) {
  bf16x4 v;
  v[0] = f2bf(a.x); v[1] = f2bf(a.y); v[2] = f2bf(a.z); v[3] = f2bf(a.w);
  return v;
}

__device__ __forceinline__ float dot4(float4 a, float4 b) {
  return a.x * b.x + a.y * b.y + a.z * b.z + a.w * b.w;
}

// async global->LDS, 16 bytes per lane. LDS dest must be uniform_base + lane*16.
__device__ __forceinline__ void async_copy16(const void* gptr, void* lptr) {
  __builtin_amdgcn_global_load_lds(
      (const __attribute__((address_space(1))) void*)gptr,
      (__attribute__((address_space(3))) void*)lptr,
      16, 0, 0);
}

// ---------------------------------------------------------------------------
// Prepass (R8, coalesced, verified). W-pass blocks [0,4096): wave owns 2
// rows = 1024 contiguous floats; X-pass blocks [4096,5120).
// ---------------------------------------------------------------------------
__global__ __launch_bounds__(256) void prep(
    const float* __restrict__ W, const float* __restrict__ C,
    const float* __restrict__ bias, const float* __restrict__ X,
    __hip_bfloat16* __restrict__ Wb, float* __restrict__ bias2,
    __hip_bfloat16* __restrict__ Xb) {
  if (blockIdx.x < 4096) {
    const int wid = (blockIdx.x * 256 + threadIdx.x) >> 6;  // wave 0..16383
    const int lane = threadIdx.x & 63;
    const int e = wid >> 10;
    const size_t base = (size_t)wid * 1024 + lane * 4;
    const float4 cA = *(const float4*)(C + e * D_DIM + lane * 4);
    const float4 cB = *(const float4*)(C + e * D_DIM + 256 + lane * 4);
    float4 w0 = *(const float4*)(W + base);
    float4 w1 = *(const float4*)(W + base + 256);
    float4 w2 = *(const float4*)(W + base + 512);
    float4 w3 = *(const float4*)(W + base + 768);
    *(bf16x4*)(Wb + base) = cvt4(w0);
    *(bf16x4*)(Wb + base + 256) = cvt4(w1);
    *(bf16x4*)(Wb + base + 512) = cvt4(w2);
    *(bf16x4*)(Wb + base + 768) = cvt4(w3);
    float dot0 = dot4(w0, cA) + dot4(w1, cB);
    float dot1 = dot4(w2, cA) + dot4(w3, cB);
#pragma unroll
    for (int off = 32; off > 0; off >>= 1) {
      dot0 += __shfl_down(dot0, off, 64);
      dot1 += __shfl_down(dot1, off, 64);
    }
    if (lane == 0) {
      bias2[2 * wid] = bias[2 * wid] - dot0;
      bias2[2 * wid + 1] = bias[2 * wid + 1] - dot1;
    }
  } else {
    const size_t t = (size_t)(blockIdx.x - 4096) * 256 + threadIdx.x;
    const size_t i0 = t * 4;
    const size_t i1 = i0 + (size_t)262144 * 4;
    float4 a0 = *(const float4*)(X + i0);
    float4 a1 = *(const float4*)(X + i1);
    *(bf16x4*)(Xb + i0) = cvt4(a0);
    *(bf16x4*)(Xb + i1) = cvt4(a1);
  }
}

// ---------------------------------------------------------------------------
// R12 GEMM. Tile 256x128, BK=64, 512 thr, 8 waves (4Mx2N), 64x64/wave.
// K-tiles g = e*8+k, g in [0,128). 3 LDS buffers rotate (49152 B each:
// A 32768 + B 16384). Slot s of row r holds global k-chunk s^(r&7)
// (R10-verified swizzle, 0 bank conflicts measured).
// Iter g (two phases, one per k-step s):
//  phase s: {8x ds_read_b128 frags (s) ; stage-issue(g+2) [A in s=0, B in
//  s=1] ; s_barrier ; lgkmcnt(0) ; setprio(1) 16 MFMA setprio(0) ;
//  [merge @ s=1,g&7==7] ; s=1 only: vmcnt(6) ; s_barrier}.
// vmcnt FIFO at tile end: outstanding = stage(g+1)(6) + stage(g+2)(6);
// vmcnt(6) drains exactly stage(g+1) -> next tile's buffer ready.
// LDS map: bufs @0/49152/98304; biasS f32[16][128] @147456. 155648 B.
// ---------------------------------------------------------------------------
__global__ __launch_bounds__(512, 2) void moe_gemm10(
    const __hip_bfloat16* __restrict__ Xb,   // [4096, 512]
    const __hip_bfloat16* __restrict__ Wb,   // [16, 2048, 512]
    const float* __restrict__ bias2,         // [16, 2048]
    float* __restrict__ out) {               // [4096, 2048]
  __shared__ __align__(16) char smem[155648];

  const int tid = threadIdx.x;
  const int lane = tid & 63;
  const int wave = tid >> 6;

  // bijective XCD swizzle: XCD x hosts mi in {2x,2x+1}, all 16 hi ->
  // A-panels L2-shared; Wb rides the LLC (proven R10 config).
  const int swz = (blockIdx.x & 7) * 32 + (blockIdx.x >> 3);
  const int mi = swz >> 4;          // 16 m-tiles
  const int hi = swz & 15;          // 16 h-tiles
  const int m0 = mi * 256;
  const int h0 = hi * 128;

  const int wm = (wave >> 1) * 64;  // 4 m-groups
  const int wn = (wave & 1) * 64;   // 2 n-groups
  const int lm = lane & 15;
  const int q = lane >> 4;

  // ---- staging source offsets (pre-swizzled): chunk n -> row n>>3,
  // slot n&7 holds global chunk (n&7)^(row&7).
  int aSrc[4], bSrc[2];
#pragma unroll
  for (int j = 0; j < 4; ++j) {
    const int n = j * 512 + tid;
    const int r = n >> 3;
    const int c = (n & 7) ^ (r & 7);
    aSrc[j] = r * D_DIM + c * 8;
  }
#pragma unroll
  for (int j = 0; j < 2; ++j) {
    const int n = j * 512 + tid;
    const int r = n >> 3;
    const int c = (n & 7) ^ (r & 7);
    bSrc[j] = r * D_DIM + c * 8;
  }

  // ---- read-side byte offsets: frag (row R, k-step s): chunk (s*4+q)
  // at slot ((s*4+q)^(R&7)).
  int aRd[4][2], bRd[4][2];
#pragma unroll
  for (int m = 0; m < 4; ++m) {
    const int R = wm + m * 16 + lm;
#pragma unroll
    for (int s = 0; s < 2; ++s)
      aRd[m][s] = R * 128 + (((s * 4 + q) ^ (R & 7)) << 4);
  }
#pragma unroll
  for (int n = 0; n < 4; ++n) {
    const int R = wn + n * 16 + lm;
#pragma unroll
    for (int s = 0; s < 2; ++s)
      bRd[n][s] = 32768 + R * 128 + (((s * 4 + q) ^ (R & 7)) << 4);
  }

#define STAGEA8(bufOff, gg)                                                  \
  {                                                                          \
    const int k0 = ((gg) & 7) << 6;                                          \
    const __hip_bfloat16* Ag = Xb + (size_t)m0 * D_DIM + k0;                 \
    _Pragma("unroll")                                                        \
    for (int j = 0; j < 4; ++j)                                              \
      async_copy16(Ag + aSrc[j], smem + (bufOff) + (j * 512 + tid) * 16);    \
  }
#define STAGEB8(bufOff, gg)                                                  \
  {                                                                          \
    const int eS = (gg) >> 3;                                                \
    const int k0 = ((gg) & 7) << 6;                                          \
    const __hip_bfloat16* Bg =                                               \
        Wb + ((size_t)eS << 20) + (size_t)h0 * D_DIM + k0;                   \
    _Pragma("unroll")                                                        \
    for (int j = 0; j < 2; ++j)                                              \
      async_copy16(Bg + bSrc[j],                                             \
                   smem + (bufOff) + 32768 + (j * 512 + tid) * 16);          \
  }

  // ---- prologue: stage tiles 0,1 + bias preload; drain tile 0 only.
  STAGEA8(0, 0);
  STAGEB8(0, 0);
  STAGEA8(49152, 1);
  STAGEB8(49152, 1);
  {
    float* bS = (float*)(smem + 147456);
#pragma unroll
    for (int j = 0; j < 4; ++j) {
      const int idx = j * 512 + tid;          // e = idx>>7, col = idx&127
      bS[idx] = bias2[((idx >> 7) << 11) + h0 + (idx & 127)];
    }
  }
  asm volatile("s_waitcnt vmcnt(6) lgkmcnt(0)" ::: "memory");
  __builtin_amdgcn_s_barrier();
  __builtin_amdgcn_sched_barrier(0);

  f32x4 sum[4][4], acc[4][4];
#pragma unroll
  for (int m = 0; m < 4; ++m)
#pragma unroll
    for (int n = 0; n < 4; ++n) {
      sum[m][n] = (f32x4){0.f, 0.f, 0.f, 0.f};
      acc[m][n] = (f32x4){0.f, 0.f, 0.f, 0.f};
    }

  int bC = 0, bN = 49152, bS2 = 98304;  // compute / next / stage targets

  for (int g = 0; g < 128; ++g) {
    // =================== phase A (k-step s=0) ===================
    {
      bf16x8 aF[4], bF[4];
#pragma unroll
      for (int m = 0; m < 4; ++m)
        aF[m] = *(const bf16x8*)(smem + bC + aRd[m][0]);
#pragma unroll
      for (int n = 0; n < 4; ++n)
        bF[n] = *(const bf16x8*)(smem + bC + bRd[n][0]);
      if (g < 126) STAGEA8(bS2, g + 2);
      __builtin_amdgcn_s_barrier();
      asm volatile("s_waitcnt lgkmcnt(0)" ::: "memory");
      __builtin_amdgcn_sched_barrier(0);
      __builtin_amdgcn_s_setprio(1);
#pragma unroll
      for (int m = 0; m < 4; ++m)
#pragma unroll
        for (int n = 0; n < 4; ++n)
          acc[m][n] = __builtin_amdgcn_mfma_f32_16x16x32_bf16(
              aF[m], bF[n], acc[m][n], 0, 0, 0);
      __builtin_amdgcn_s_setprio(0);
      __builtin_amdgcn_s_barrier();
      __builtin_amdgcn_sched_barrier(0);
    }
    // =================== phase B (k-step s=1) ===================
    {
      bf16x8 aF[4], bF[4];
#pragma unroll
      for (int m = 0; m < 4; ++m)
        aF[m] = *(const bf16x8*)(smem + bC + aRd[m][1]);
#pragma unroll
      for (int n = 0; n < 4; ++n)
        bF[n] = *(const bf16x8*)(smem + bC + bRd[n][1]);
      if (g < 126) STAGEB8(bS2, g + 2);
      __builtin_amdgcn_s_barrier();
      asm volatile("s_waitcnt lgkmcnt(0)" ::: "memory");
      __builtin_amdgcn_sched_barrier(0);
      __builtin_amdgcn_s_setprio(1);
#pragma unroll
      for (int m = 0; m < 4; ++m)
#pragma unroll
        for (int n = 0; n < 4; ++n)
          acc[m][n] = __builtin_amdgcn_mfma_f32_16x16x32_bf16(
              aF[m], bF[n], acc[m][n], 0, 0, 0);
      __builtin_amdgcn_s_setprio(0);

      if ((g & 7) == 7) {  // expert merge (uniform branch, register-only)
        const float* bv =
            (const float*)(smem + 147456) + ((g >> 3) << 7) + wn + lm;
#pragma unroll
        for (int n = 0; n < 4; ++n) {
          const float bvn = bv[n * 16];
#pragma unroll
          for (int m = 0; m < 4; ++m)
#pragma unroll
            for (int u = 0; u < 4; ++u) {
              sum[m][n][u] += fmaxf(acc[m][n][u] + bvn, 0.f);
              acc[m][n][u] = 0.f;
            }
        }
      }

      // counted drain: leaves stage(g+2)'s 6 loads in flight.
      if (g < 126)
        asm volatile("s_waitcnt vmcnt(6)" ::: "memory");
      else
        asm volatile("s_waitcnt vmcnt(0)" ::: "memory");
      __builtin_amdgcn_s_barrier();
      __builtin_amdgcn_sched_barrier(0);
    }

    const int t_ = bC; bC = bN; bN = bS2; bS2 = t_;
  }
#undef STAGEA8
#undef STAGEB8

  // write: C/D layout col=lane&15, row=(lane>>4)*4+reg  [verified m89/m91]
#pragma unroll
  for (int m = 0; m < 4; ++m)
#pragma unroll
    for (int n = 0; n < 4; ++n)
#pragma unroll
      for (int u = 0; u < 4; ++u)
        out[(size_t)(m0 + wm + m * 16 + q * 4 + u) * H_DIM +
            h0 + wn + n * 16 + lm] = sum[m][n][u];
}

// ---------------------------------------------------------------------------
// Fallback path A: R6-verified GEMM (167 us, 4 blocks/CU).
// ---------------------------------------------------------------------------
__global__ __launch_bounds__(256, 4) void moe_gemm(
    const __hip_bfloat16* __restrict__ Xb, const __hip_bfloat16* __restrict__ Wb,
    const float* __restrict__ bias2, float* __restrict__ out) {
  __shared__ __align__(16) __hip_bfloat16 As[2][128 * 32];
  __shared__ __align__(16) __hip_bfloat16 Bs[2][2][64 * 32];
  __shared__ __align__(16) float biasS[E_DIM * 64];

  const int tid = threadIdx.x;
  const int lane = tid & 63;
  const int wave = tid >> 6;
  const int hi = blockIdx.x & 31;
  const int mi = blockIdx.x >> 5;
  const int m0 = mi * 128;
  const int h0 = hi * 64;

  for (int idx = tid; idx < E_DIM * 64; idx += 256) {
    biasS[idx] = bias2[((idx >> 6) << 11) + h0 + (idx & 63)];
  }

  const int wm = (wave & 1) * 64;
  const int wn = (wave >> 1) * 32;
  const int lm = lane & 15;
  const int q = lane >> 4;

  const int r = tid >> 2;
  const int fr = (r >> 1) & 3;
  const int col = (((tid & 3) ^ fr)) << 3;
  const size_t aOff0 = (size_t)(m0 + r) * D_DIM + col;
  const size_t aOff1 = (size_t)(m0 + r + 64) * D_DIM + col;
  const size_t bOff = (size_t)(h0 + r) * D_DIM + col;
  const int ldA0 = tid * 8;
  const int ldA1 = (tid + 256) * 8;
  const int ldB = tid * 8;

  int offA[4], offB[2];
#pragma unroll
  for (int i = 0; i < 4; ++i) {
    const int R = wm + i * 16 + lm;
    offA[i] = R * 32 + ((q ^ ((R >> 1) & 3)) << 3);
  }
#pragma unroll
  for (int j = 0; j < 2; ++j) {
    const int R = wn + j * 16 + lm;
    offB[j] = R * 32 + ((q ^ ((R >> 1) & 3)) << 3);
  }

  f32x4 sum[4][2], acc0[4][2], acc1[4][2];
#pragma unroll
  for (int i = 0; i < 4; ++i)
#pragma unroll
    for (int j = 0; j < 2; ++j) {
      sum[i][j] = (f32x4){0.f, 0.f, 0.f, 0.f};
      acc0[i][j] = (f32x4){0.f, 0.f, 0.f, 0.f};
      acc1[i][j] = (f32x4){0.f, 0.f, 0.f, 0.f};
    }

#define STAGE(buf, tt)                                                      \
  {                                                                         \
    const int kk = ((tt) & 15) << 5;                                        \
    const __hip_bfloat16* Bb = Wb + ((size_t)((tt) >> 4) << 21) + bOff + kk;\
    async_copy16(Xb + aOff0 + kk, &As[buf][ldA0]);                          \
    async_copy16(Xb + aOff1 + kk, &As[buf][ldA1]);                          \
    async_copy16(Bb, &Bs[buf][0][ldB]);                                     \
    async_copy16(Bb + ((size_t)1 << 20), &Bs[buf][1][ldB]);                 \
  }

  STAGE(0, 0);
  __syncthreads();

  for (int t = 0; t < 128; ++t) {
    const int cur = t & 1;
    if (t < 127) STAGE(cur ^ 1, t + 1);

    bf16x8 af[4];
#pragma unroll
    for (int i = 0; i < 4; ++i) af[i] = *(const bf16x8*)&As[cur][offA[i]];

#pragma unroll
    for (int j = 0; j < 2; ++j) {
      const bf16x8 b0 = *(const bf16x8*)&Bs[cur][0][offB[j]];
#pragma unroll
      for (int i = 0; i < 4; ++i)
        acc0[i][j] = __builtin_amdgcn_mfma_f32_16x16x32_bf16(
            af[i], b0, acc0[i][j], 0, 0, 0);
      const bf16x8 b1 = *(const bf16x8*)&Bs[cur][1][offB[j]];
#pragma unroll
      for (int i = 0; i < 4; ++i)
        acc1[i][j] = __builtin_amdgcn_mfma_f32_16x16x32_bf16(
            af[i], b1, acc1[i][j], 0, 0, 0);
    }

    if ((t & 15) == 15) {
      const int pair = t >> 4;
#pragma unroll
      for (int j = 0; j < 2; ++j) {
        const float bv0 = biasS[(2 * pair) * 64 + wn + j * 16 + lm];
        const float bv1 = biasS[(2 * pair + 1) * 64 + wn + j * 16 + lm];
#pragma unroll
        for (int i = 0; i < 4; ++i)
#pragma unroll
          for (int u = 0; u < 4; ++u) {
            sum[i][j][u] += fmaxf(acc0[i][j][u] + bv0, 0.f) +
                            fmaxf(acc1[i][j][u] + bv1, 0.f);
            acc0[i][j][u] = 0.f;
            acc1[i][j][u] = 0.f;
          }
      }
    }

    __syncthreads();
  }
#undef STAGE

  const int rbase = q * 4;
#pragma unroll
  for (int i = 0; i < 4; ++i)
#pragma unroll
    for (int j = 0; j < 2; ++j)
#pragma unroll
      for (int u = 0; u < 4; ++u)
        out[(size_t)(m0 + wm + i * 16 + rbase + u) * H_DIM + h0 + wn + j * 16 + lm] =
            sum[i][j][u];
}

// ---------------------------------------------------------------------------
// Fallback path B (workspace too small): naive fp32.
// ---------------------------------------------------------------------------
__global__ __launch_bounds__(256) void naive_kernel(
    const float* __restrict__ x, const float* __restrict__ c,
    const float* __restrict__ W, const float* __restrict__ bias,
    float* __restrict__ out) {
  const int idx = blockIdx.x * 256 + threadIdx.x;
  const int b = idx >> 11;
  const int h = idx & (H_DIM - 1);
  const float* xr = x + (size_t)b * D_DIM;
  float s = 0.f;
  for (int e = 0; e < E_DIM; ++e) {
    const float* wr = W + ((size_t)e * H_DIM + h) * D_DIM;
    const float* cr = c + (size_t)e * D_DIM;
    float acc = bias[e * H_DIM + h];
    for (int d = 0; d < D_DIM; ++d) acc += (xr[d] - cr[d]) * wr[d];
    s += fmaxf(acc, 0.f);
  }
  out[idx] = s;
}

extern "C" void kernel_launch(void* const* d_in, const int* in_sizes, int n_in,
                              void* d_out, int out_size, void* d_ws, size_t ws_size,
                              hipStream_t stream) {
  const float* x = (const float*)d_in[0];     // [4096, 512]
  const float* c = (const float*)d_in[1];     // [16, 512]
  const float* W = (const float*)d_in[2];     // [16, 2048, 512]
  const float* b = (const float*)d_in[3];     // [16, 2048]
  float* out = (float*)d_out;                 // [4096, 2048]

  const size_t sz_wb = (size_t)E_DIM * H_DIM * D_DIM * 2;  // 32 MB
  const size_t sz_xb = (size_t)B_DIM * D_DIM * 2;          // 4 MB
  const size_t sz_b2 = (size_t)E_DIM * H_DIM * 4;          // 128 KB
  const size_t need = sz_wb + sz_xb + sz_b2;

  if (ws_size >= need) {
    __hip_bfloat16* Wb = (__hip_bfloat16*)((char*)d_ws);
    __hip_bfloat16* Xb = (__hip_bfloat16*)((char*)d_ws + sz_wb);
    float* bias2 = (float*)((char*)d_ws + sz_wb + sz_xb);

    // one-time: verify 152KB-LDS kernel is launchable (>=1 block/CU)
    static int g10_ok = -1;
    if (g10_ok < 0) {
      int nb = 0;
      hipError_t e = hipOccupancyMaxActiveBlocksPerMultiprocessor(
          &nb, moe_gemm10, 512, 0);
      g10_ok = (e == hipSuccess && nb >= 1) ? 1 : 0;
    }

    prep<<<5120, 256, 0, stream>>>(W, c, b, x, Wb, bias2, Xb);
    if (g10_ok) {
      moe_gemm10<<<256, 512, 0, stream>>>(Xb, Wb, bias2, out);
    } else {
      moe_gemm<<<1024, 256, 0, stream>>>(Xb, Wb, bias2, out);
    }
  } else {
    naive_kernel<<<(B_DIM * H_DIM) / 256, 256, 0, stream>>>(x, c, W, b, out);
  }
}